// Round 14
// baseline (104.915 us; speedup 1.0000x reference)
//
#include <hip/hip_runtime.h>
#include <hip/hip_bf16.h>

typedef __hip_bfloat16 bf16;
typedef __attribute__((ext_vector_type(8))) short short8;
typedef __attribute__((ext_vector_type(4))) float f32x4;

#define SL 1024
#define DIM 512
#define NH 8
#define HD 64
#define NBUCK 128

__device__ __forceinline__ float silu_f(float x) { return x / (1.0f + __expf(-x)); }

__device__ __forceinline__ short f2bf(float x) {
  bf16 b = __float2bfloat16(x);
  return *reinterpret_cast<short*>(&b);
}

__device__ __forceinline__ void gld_lds16(const void* g, void* l) {
  __builtin_amdgcn_global_load_lds(
      (const __attribute__((address_space(1))) void*)g,
      (__attribute__((address_space(3))) void*)l, 16, 0, 0);
}

// ---------- fused prep: weights f32->bf16 (blocks 0..1279) + rmsnorm (blocks 1280..2303) ----------
__global__ __launch_bounds__(256) void prep_k(const float* __restrict__ s0, const float* __restrict__ s1,
                                              const float* __restrict__ s2, const float* __restrict__ s3,
                                              const float* __restrict__ s4, bf16* __restrict__ wdst,
                                              const float* __restrict__ hidden, const float* __restrict__ ln_w,
                                              bf16* __restrict__ hb) {
  int bx = blockIdx.x;
  if (bx < 1280) {
    int wsel = bx >> 8;
    const float* src = wsel == 0 ? s0 : wsel == 1 ? s1 : wsel == 2 ? s2 : wsel == 3 ? s3 : s4;
    int i = ((bx & 255) * 256 + threadIdx.x) * 4;
    float4 v = *(const float4*)(src + i);
    bf16* d = wdst + (size_t)wsel * DIM * DIM + i;
    d[0] = __float2bfloat16(v.x);
    d[1] = __float2bfloat16(v.y);
    d[2] = __float2bfloat16(v.z);
    d[3] = __float2bfloat16(v.w);
  } else {
    int row = (bx - 1280) * 4 + (threadIdx.x >> 6);  // one row per wave
    int l = threadIdx.x & 63;
    const float4* xr = (const float4*)(hidden + (size_t)row * DIM);
    float4 v0 = xr[l], v1 = xr[l + 64];
    float s = v0.x*v0.x + v0.y*v0.y + v0.z*v0.z + v0.w*v0.w
            + v1.x*v1.x + v1.y*v1.y + v1.z*v1.z + v1.w*v1.w;
    #pragma unroll
    for (int o = 32; o; o >>= 1) s += __shfl_xor(s, o);
    float sc = rsqrtf(s * (1.0f / DIM) + 1e-6f);
    bf16* orow = hb + (size_t)row * DIM;
    int c0 = l * 4, c1 = 256 + l * 4;
    orow[c0 + 0] = __float2bfloat16(v0.x * sc * ln_w[c0 + 0]);
    orow[c0 + 1] = __float2bfloat16(v0.y * sc * ln_w[c0 + 1]);
    orow[c0 + 2] = __float2bfloat16(v0.z * sc * ln_w[c0 + 2]);
    orow[c0 + 3] = __float2bfloat16(v0.w * sc * ln_w[c0 + 3]);
    orow[c1 + 0] = __float2bfloat16(v1.x * sc * ln_w[c1 + 0]);
    orow[c1 + 1] = __float2bfloat16(v1.y * sc * ln_w[c1 + 1]);
    orow[c1 + 2] = __float2bfloat16(v1.z * sc * ln_w[c1 + 2]);
    orow[c1 + 3] = __float2bfloat16(v1.w * sc * ln_w[c1 + 3]);
  }
}

// ---------- q,k,u,vT = silu(h @ W^T), 128x64 tiles (one head per tile), BK=64 ----------
// grid (256, 4): bm = x&31 (XCD swizzle), bn = x>>5, mode = y
// Also absorbs the attn strict-upper zero-fill (896 tiles over first 896 blocks) in
// its write-bandwidth shadow: fire-and-forget stores issued before the compute loop.
__global__ __launch_bounds__(256) void gemm_qkvu_k(const bf16* __restrict__ hb,
                                                   const bf16* __restrict__ wb,
                                                   bf16* __restrict__ q, bf16* __restrict__ k,
                                                   bf16* __restrict__ vT, bf16* __restrict__ u,
                                                   float* __restrict__ attn) {
  int mode = blockIdx.y;
  int bm = blockIdx.x & 31, bn = blockIdx.x >> 5;
  int t = threadIdx.x, w = t >> 6, l = t & 63;
  int ln = l & 15, l4 = (l >> 4) * 4;
  __shared__ __align__(16) short lds[12288];  // A [128][64] + B [64][64]; reused 128*65 transpose

  // zero-fill one strict-upper attn tile (jobs 0..895: bh = fid&31, tile idx = fid>>5)
  {
    int fid = mode * 256 + blockIdx.x;
    if (fid < 896) {
      int bh = fid & 31, idx = fid >> 5;
      int zi = 0, a2 = 0;
      while (a2 + (7 - zi) <= idx) { a2 += 7 - zi; ++zi; }
      int zj = zi + 1 + (idx - a2);
      float* arow = attn + (size_t)bh * SL * SL;
      float4 z4 = make_float4(0.f, 0.f, 0.f, 0.f);
      #pragma unroll
      for (int rep = 0; rep < 16; ++rep) {
        int flat = rep * 256 + t;
        int row = flat >> 5, c4 = flat & 31;
        *(float4*)(arow + (size_t)(zi * 128 + row) * SL + zj * 128 + c4 * 4) = z4;
      }
    }
  }

  const bf16* wbm = wb + (size_t)mode * DIM * DIM;
  f32x4 acc[2][4];
  #pragma unroll
  for (int m = 0; m < 2; ++m)
    #pragma unroll
    for (int n = 0; n < 4; ++n) { f32x4 z = {0.f, 0.f, 0.f, 0.f}; acc[m][n] = z; }

  int srow8 = l >> 3;
  int scol = ((l & 7) ^ srow8) * 8;
  for (int kt = 0; kt < 8; ++kt) {
    if (kt) __syncthreads();
    #pragma unroll
    for (int i = 0; i < 6; ++i) {
      int s = i * 4 + w;                    // 0..23; 0-15 A (128 rows), 16-23 B (64 rows)
      int row = (s < 16 ? s : s - 16) * 8 + srow8;
      int col = kt * 64 + scol;
      const bf16* g = (s < 16)
          ? (hb + (size_t)(bm * 128 + row) * DIM + col)
          : (wbm + (size_t)(bn * 64 + row) * DIM + col);
      gld_lds16(g, lds + s * 512 + l * 8);
    }
    __syncthreads();
    #pragma unroll
    for (int kk = 0; kk < 2; ++kk) {
      short8 a[2], b[4];
      #pragma unroll
      for (int m = 0; m < 2; ++m) {
        int row = w * 32 + m * 16 + ln;
        int c = ((kk * 4 + (l >> 4)) ^ (row & 7)) * 8;
        a[m] = *(const short8*)(lds + row * 64 + c);
      }
      #pragma unroll
      for (int n = 0; n < 4; ++n) {
        int row = n * 16 + ln;
        int c = ((kk * 4 + (l >> 4)) ^ (row & 7)) * 8;
        b[n] = *(const short8*)(lds + 8192 + row * 64 + c);
      }
      #pragma unroll
      for (int m = 0; m < 2; ++m)
        #pragma unroll
        for (int n = 0; n < 4; ++n)
          acc[m][n] = __builtin_amdgcn_mfma_f32_16x16x32_bf16(a[m], b[n], acc[m][n], 0, 0, 0);
    }
  }

  if (mode == 2) {
    // tile = one head's [128 rows]x[64 d]; transpose via LDS into vT[b,h,d,l]
    __syncthreads();                   // gemm reads done, LDS free
    #pragma unroll
    for (int m = 0; m < 2; ++m)
      #pragma unroll
      for (int n = 0; n < 4; ++n)
        #pragma unroll
        for (int j = 0; j < 4; ++j) {
          int rl = w * 32 + m * 16 + l4 + j;   // 0..127
          int cl = n * 16 + ln;                // 0..63
          lds[rl * 65 + cl] = f2bf(silu_f(acc[m][n][j]));
        }
    __syncthreads();
    int b = bm >> 3, li0 = (bm & 7) * 128;
    int d = t >> 2, seg = t & 3;
    bf16* dst = vT + ((size_t)(b * NH + bn) * HD + d) * SL + li0 + seg * 32;
    short8 y0, y1, y2, y3;
    #pragma unroll
    for (int qq = 0; qq < 8; ++qq) {
      y0[qq] = lds[(seg * 32 + qq) * 65 + d];
      y1[qq] = lds[(seg * 32 + 8 + qq) * 65 + d];
      y2[qq] = lds[(seg * 32 + 16 + qq) * 65 + d];
      y3[qq] = lds[(seg * 32 + 24 + qq) * 65 + d];
    }
    *(short8*)dst = y0; *(short8*)(dst + 8) = y1;
    *(short8*)(dst + 16) = y2; *(short8*)(dst + 24) = y3;
    return;
  }

  #pragma unroll
  for (int m = 0; m < 2; ++m)
    #pragma unroll
    for (int n = 0; n < 4; ++n)
      #pragma unroll
      for (int j = 0; j < 4; ++j) {
        int rg = bm * 128 + w * 32 + m * 16 + l4 + j;
        int c64 = n * 16 + ln;
        bf16 val = __float2bfloat16(silu_f(acc[m][n][j]));
        int b = rg >> 10, li = rg & 1023;
        if (mode == 0)      q[((size_t)(b * NH + bn) * SL + li) * HD + c64] = val;
        else if (mode == 1) k[((size_t)(b * NH + bn) * SL + li) * HD + c64] = val;
        else                u[(size_t)rg * DIM + bn * 64 + c64] = val;
      }
}

// ---------- attn = silu(q k^T + bias)/L, lower-triangle tiles only ----------
__global__ __launch_bounds__(256) void qk_attn_k(const bf16* __restrict__ q,
                                                 const bf16* __restrict__ k,
                                                 const int* __restrict__ ts,
                                                 const float* __restrict__ ts_w,
                                                 const float* __restrict__ pos_w,
                                                 float* __restrict__ attn) {
  int bh = blockIdx.y, x = blockIdx.x;
  int ti = 0, accx = 0;
  while (accx + ti + 1 <= x) { accx += ti + 1; ++ti; }
  int tj = x - accx;                   // tj <= ti
  int t = threadIdx.x, w = t >> 6, l = t & 63;
  int ln = l & 15, l4 = (l >> 4) * 4;
  int wr = (w >> 1) * 64, wc = (w & 1) * 64;
  float* arow = attn + (size_t)bh * SL * SL;

  __shared__ __align__(16) short lds[16384];  // q tile [128][64], k tile [128][64]
  __shared__ float tw_l[NBUCK + 1];
  __shared__ float pw_l[255];
  __shared__ int tsi_l[128], tsj_l[128];

  const int* tsb = ts + (size_t)(bh >> 3) * SL;
  if (t < NBUCK + 1) tw_l[t] = ts_w[t];
  if (t < 255) pw_l[t] = pos_w[896 + (tj - ti) * 128 + t];
  if (t < 128) tsi_l[t] = tsb[min(ti * 128 + t + 1, SL - 1)];
  else         tsj_l[t - 128] = tsb[tj * 128 + (t - 128)];

  #pragma unroll
  for (int i = 0; i < 8; ++i) {
    int s = i * 4 + w;                 // 0..31; 0-15 q, 16-31 k
    int row = (s & 15) * 8 + (l >> 3);
    int col = ((l & 7) ^ (l >> 3)) * 8;   // pre-swizzled source (row&7 == l>>3)
    const bf16* g = (s < 16)
        ? (q + (size_t)bh * SL * HD + (size_t)(ti * 128 + row) * HD + col)
        : (k + (size_t)bh * SL * HD + (size_t)(tj * 128 + row) * HD + col);
    gld_lds16(g, lds + s * 512 + l * 8);
  }
  __syncthreads();

  f32x4 acc[4][4];
  #pragma unroll
  for (int m = 0; m < 4; ++m)
    #pragma unroll
    for (int n = 0; n < 4; ++n) { f32x4 z = {0.f, 0.f, 0.f, 0.f}; acc[m][n] = z; }
  #pragma unroll
  for (int kk = 0; kk < 2; ++kk) {        // chunk base 0 / 4
    short8 a[4], b[4];
    #pragma unroll
    for (int m = 0; m < 4; ++m) {
      int row = wr + m * 16 + ln;
      int c = ((kk * 4 + (l >> 4)) ^ (row & 7)) * 8;
      a[m] = *(const short8*)(lds + row * 64 + c);
    }
    #pragma unroll
    for (int n = 0; n < 4; ++n) {
      int row = wc + n * 16 + ln;
      int c = ((kk * 4 + (l >> 4)) ^ (row & 7)) * 8;
      b[n] = *(const short8*)(lds + 8192 + row * 64 + c);
    }
    #pragma unroll
    for (int m = 0; m < 4; ++m)
      #pragma unroll
      for (int n = 0; n < 4; ++n)
        acc[m][n] = __builtin_amdgcn_mfma_f32_16x16x32_bf16(a[m], b[n], acc[m][n], 0, 0, 0);
  }

  const float LSC = 2.30281455f;       // ln2 / 0.301
  #pragma unroll
  for (int m = 0; m < 4; ++m)
    #pragma unroll
    for (int j = 0; j < 4; ++j) {
      int il = wr + m * 16 + l4 + j;
      int tsi = tsi_l[il];
      int i = ti * 128 + il;
      #pragma unroll
      for (int n = 0; n < 4; ++n) {
        int jl = wc + n * 16 + ln;
        int jj = tj * 128 + jl;
        float v = acc[m][n][j];
        int dt = tsi - tsj_l[jl];
        float adf = fmaxf(fabsf((float)dt), 1.0f);
        int bucket = (int)(__log2f(adf) * LSC);
        bucket = bucket < 0 ? 0 : (bucket > NBUCK ? NBUCK : bucket);
        float bias = tw_l[bucket] + pw_l[jl - il + 127];
        float o = (jj <= i) ? silu_f(v + bias) * (1.0f / (float)SL) : 0.0f;
        arow[(size_t)i * SL + jj] = o;
      }
    }
}

// ---------- partial attn_out, balanced chunks (<=6 kt64 units), 3 partial slots ----------
__global__ __launch_bounds__(256) void pv_k(const float* __restrict__ attn,
                                            const bf16* __restrict__ vT,
                                            float* __restrict__ ao0,
                                            float* __restrict__ ao1,
                                            float* __restrict__ ao2) {
  // chunk tables: per bm (0..7) the 2*(bm+1) kt64 units are split into <=3 chunks
  static const char cb_bm[17] = {0,1,2,2,3,3,4,4,5,5,5,6,6,6,7,7,7};
  static const char cb_lo[17] = {0,0,0,3,0,4,0,5,0,4,8,0,5,10,0,6,11};
  static const char cb_hi[17] = {2,4,3,6,4,8,5,10,4,8,12,5,10,14,6,11,16};
  static const char cb_sl[17] = {0,0,0,1,0,1,0,1,0,1,2,0,1,2,0,1,2};
  int ch = blockIdx.x, bh = blockIdx.y;
  int bm = cb_bm[ch], klo = cb_lo[ch], khi = cb_hi[ch], slot = cb_sl[ch];
  int t = threadIdx.x, w = t >> 6, l = t & 63;
  int ln = l & 15, l4 = (l >> 4) * 4;
  __shared__ __align__(16) short lds[12288];  // A [128][64] + B [64][64]
  const float* arow = attn + (size_t)bh * SL * SL;
  const bf16* vrow = vT + (size_t)bh * HD * SL;
  f32x4 acc[2][4];
  #pragma unroll
  for (int m = 0; m < 2; ++m)
    #pragma unroll
    for (int n = 0; n < 4; ++n) { f32x4 z = {0.f, 0.f, 0.f, 0.f}; acc[m][n] = z; }

  int srow8 = l >> 3;
  int swc = ((l & 7) ^ srow8) * 8;          // swizzled chunk (row&7 == l>>3)
  for (int kt = klo; kt < khi; ++kt) {
    if (kt > klo) __syncthreads();
    // A tile: 16 slices (4/wave) from f32 attn, reg-converted to bf16, swizzled ds_write
    #pragma unroll
    for (int ss = 0; ss < 4; ++ss) {
      int s = w * 4 + ss;                   // 0..15
      int row = s * 8 + srow8;              // 0..127
      const float* g = arow + (size_t)(bm * 128 + row) * SL + kt * 64 + (l & 7) * 8;
      float4 f0 = *(const float4*)g;
      float4 f1 = *(const float4*)(g + 4);
      short8 vv;
      vv[0] = f2bf(f0.x); vv[1] = f2bf(f0.y); vv[2] = f2bf(f0.z); vv[3] = f2bf(f0.w);
      vv[4] = f2bf(f1.x); vv[5] = f2bf(f1.y); vv[6] = f2bf(f1.z); vv[7] = f2bf(f1.w);
      *(short8*)(lds + row * 64 + swc) = vv;
    }
    // B tile: 8 slices (2/wave) from bf16 vT via async LDS, pre-swizzled source
    #pragma unroll
    for (int i = 0; i < 2; ++i) {
      int s2 = i * 4 + w;                   // 0..7
      int row = s2 * 8 + srow8;             // 0..63
      gld_lds16(vrow + (size_t)row * SL + kt * 64 + swc, lds + 8192 + s2 * 512 + l * 8);
    }
    __syncthreads();
    #pragma unroll
    for (int kk = 0; kk < 2; ++kk) {
      short8 a[2], b[4];
      #pragma unroll
      for (int m = 0; m < 2; ++m) {
        int row = w * 32 + m * 16 + ln;
        int c = ((kk * 4 + (l >> 4)) ^ (row & 7)) * 8;
        a[m] = *(const short8*)(lds + row * 64 + c);
      }
      #pragma unroll
      for (int n = 0; n < 4; ++n) {
        int row = n * 16 + ln;
        int c = ((kk * 4 + (l >> 4)) ^ (row & 7)) * 8;
        b[n] = *(const short8*)(lds + 8192 + row * 64 + c);
      }
      #pragma unroll
      for (int m = 0; m < 2; ++m)
        #pragma unroll
        for (int n = 0; n < 4; ++n)
          acc[m][n] = __builtin_amdgcn_mfma_f32_16x16x32_bf16(a[m], b[n], acc[m][n], 0, 0, 0);
    }
  }

  float* aop = slot == 0 ? ao0 : (slot == 1 ? ao1 : ao2);
  int b = bh >> 3, hh = bh & 7;
  #pragma unroll
  for (int m = 0; m < 2; ++m)
    #pragma unroll
    for (int n = 0; n < 4; ++n)
      #pragma unroll
      for (int j = 0; j < 4; ++j) {
        int i = bm * 128 + w * 32 + m * 16 + l4 + j;
        int dd = n * 16 + ln;
        aop[((size_t)(b * SL + i)) * DIM + hh * HD + dd] = acc[m][n][j];
      }
}

// ---------- gated = u * rmsnorm(sum of partials) * attn_ln_w ----------
// partial count per 128-row band: {1,1,2,2,2,3,3,3}
__global__ void gated_k(const float* __restrict__ ao0, const float* __restrict__ ao1,
                        const float* __restrict__ ao2, const bf16* __restrict__ u,
                        const float* __restrict__ w, bf16* __restrict__ g) {
  int row = blockIdx.x, l = threadIdx.x;  // 64 threads
  int bmRow = (row & 1023) >> 7;
  const float4* ar0 = (const float4*)(ao0 + (size_t)row * DIM);
  const float4* ar1 = (const float4*)(ao1 + (size_t)row * DIM);
  const float4* ar2 = (const float4*)(ao2 + (size_t)row * DIM);
  float4 a0 = ar0[l], a1 = ar0[l + 64];
  if (bmRow >= 2) {
    float4 p0 = ar1[l], p1 = ar1[l + 64];
    a0.x += p0.x; a0.y += p0.y; a0.z += p0.z; a0.w += p0.w;
    a1.x += p1.x; a1.y += p1.y; a1.z += p1.z; a1.w += p1.w;
  }
  if (bmRow >= 5) {
    float4 p0 = ar2[l], p1 = ar2[l + 64];
    a0.x += p0.x; a0.y += p0.y; a0.z += p0.z; a0.w += p0.w;
    a1.x += p1.x; a1.y += p1.y; a1.z += p1.z; a1.w += p1.w;
  }
  float s = a0.x*a0.x + a0.y*a0.y + a0.z*a0.z + a0.w*a0.w
          + a1.x*a1.x + a1.y*a1.y + a1.z*a1.z + a1.w*a1.w;
  #pragma unroll
  for (int o = 32; o; o >>= 1) s += __shfl_xor(s, o);
  float sc = rsqrtf(s * (1.0f / DIM) + 1e-6f);
  const bf16* ur = u + (size_t)row * DIM;
  bf16* gr = g + (size_t)row * DIM;
  int c0 = l * 4, c1 = 256 + l * 4;
  gr[c0 + 0] = __float2bfloat16(__bfloat162float(ur[c0 + 0]) * a0.x * sc * w[c0 + 0]);
  gr[c0 + 1] = __float2bfloat16(__bfloat162float(ur[c0 + 1]) * a0.y * sc * w[c0 + 1]);
  gr[c0 + 2] = __float2bfloat16(__bfloat162float(ur[c0 + 2]) * a0.z * sc * w[c0 + 2]);
  gr[c0 + 3] = __float2bfloat16(__bfloat162float(ur[c0 + 3]) * a0.w * sc * w[c0 + 3]);
  gr[c1 + 0] = __float2bfloat16(__bfloat162float(ur[c1 + 0]) * a1.x * sc * w[c1 + 0]);
  gr[c1 + 1] = __float2bfloat16(__bfloat162float(ur[c1 + 1]) * a1.y * sc * w[c1 + 1]);
  gr[c1 + 2] = __float2bfloat16(__bfloat162float(ur[c1 + 2]) * a1.z * sc * w[c1 + 2]);
  gr[c1 + 3] = __float2bfloat16(__bfloat162float(ur[c1 + 3]) * a1.w * sc * w[c1 + 3]);
}

// ---------- out = residual + gated @ wo^T, 128x64 tiles, BK=64, XCD-swizzled ----------
__global__ __launch_bounds__(256) void gemm_out_k(const bf16* __restrict__ gated,
                                                  const bf16* __restrict__ wob,
                                                  const float* __restrict__ residual,
                                                  float* __restrict__ out) {
  int bm = blockIdx.x & 31, bn = blockIdx.x >> 5;
  int t = threadIdx.x, w = t >> 6, l = t & 63;
  int ln = l & 15, l4 = (l >> 4) * 4;
  __shared__ __align__(16) short lds[12288];  // A [128][64] + B [64][64]
  f32x4 acc[2][4];
  #pragma unroll
  for (int m = 0; m < 2; ++m)
    #pragma unroll
    for (int n = 0; n < 4; ++n) { f32x4 z = {0.f, 0.f, 0.f, 0.f}; acc[m][n] = z; }

  int srow8 = l >> 3;
  int scol = ((l & 7) ^ srow8) * 8;
  for (int kt = 0; kt < 8; ++kt) {
    if (kt) __syncthreads();
    #pragma unroll
    for (int i = 0; i < 6; ++i) {
      int s = i * 4 + w;                    // 0..23; 0-15 A (128 rows), 16-23 B (64 rows)
      int row = (s < 16 ? s : s - 16) * 8 + srow8;
      int col = kt * 64 + scol;
      const bf16* g = (s < 16)
          ? (gated + (size_t)(bm * 128 + row) * DIM + col)
          : (wob + (size_t)(bn * 64 + row) * DIM + col);
      gld_lds16(g, lds + s * 512 + l * 8);
    }
    __syncthreads();
    #pragma unroll
    for (int kk = 0; kk < 2; ++kk) {
      short8 a[2], b[4];
      #pragma unroll
      for (int m = 0; m < 2; ++m) {
        int row = w * 32 + m * 16 + ln;
        int c = ((kk * 4 + (l >> 4)) ^ (row & 7)) * 8;
        a[m] = *(const short8*)(lds + row * 64 + c);
      }
      #pragma unroll
      for (int n = 0; n < 4; ++n) {
        int row = n * 16 + ln;
        int c = ((kk * 4 + (l >> 4)) ^ (row & 7)) * 8;
        b[n] = *(const short8*)(lds + 8192 + row * 64 + c);
      }
      #pragma unroll
      for (int m = 0; m < 2; ++m)
        #pragma unroll
        for (int n = 0; n < 4; ++n)
          acc[m][n] = __builtin_amdgcn_mfma_f32_16x16x32_bf16(a[m], b[n], acc[m][n], 0, 0, 0);
    }
  }

  #pragma unroll
  for (int m = 0; m < 2; ++m)
    #pragma unroll
    for (int n = 0; n < 4; ++n)
      #pragma unroll
      for (int j = 0; j < 4; ++j) {
        int rg = bm * 128 + w * 32 + m * 16 + l4 + j;
        int cg = bn * 64 + n * 16 + ln;
        size_t idx = (size_t)rg * DIM + cg;
        out[idx] = acc[m][n][j] + residual[idx];
      }
}

extern "C" void kernel_launch(void* const* d_in, const int* in_sizes, int n_in,
                              void* d_out, int out_size, void* d_ws, size_t ws_size,
                              hipStream_t stream) {
  const float* hidden    = (const float*)d_in[0];
  // d_in[1] = attention_mask (causal tril) — recomputed analytically
  const int*   ts        = (const int*)d_in[2];
  const float* ln_w      = (const float*)d_in[3];
  const float* attn_ln_w = (const float*)d_in[4];
  const float* wq        = (const float*)d_in[5];
  const float* wk        = (const float*)d_in[6];
  const float* wv        = (const float*)d_in[7];
  const float* wu        = (const float*)d_in[8];
  const float* wo        = (const float*)d_in[9];
  const float* ts_w      = (const float*)d_in[10];
  const float* pos_w     = (const float*)d_in[11];

  // OUTPUTS ARE FLOAT32: out [4,1024,512] then attn [4,8,1024,1024]
  float* out  = (float*)d_out;
  float* attn = out + 2097152;

  // workspace (~44.6 MiB < proven 56 MiB); ao2 overlays hb+q (dead by pv time)
  bf16* wb    = (bf16*)d_ws;           // 5 * 512*512
  bf16* hb    = wb + 5 * DIM * DIM;    // [4096,512]
  bf16* q     = hb + 2097152;          // [b,h,l,d]
  bf16* k     = q + 2097152;
  bf16* vT    = k + 2097152;           // [b,h,d,l] (written directly by gemm_qkvu)
  bf16* u     = vT + 2097152;          // [4096,512]
  bf16* gated = u + 2097152;           // [4096,512]
  float* ao0  = (float*)(gated + 2097152);  // [4096,512] f32
  float* ao1  = ao0 + 2097152;              // [4096,512] f32
  float* ao2  = (float*)hb;                 // overlay: hb(4MB)+q(4MB) dead after qk_attn

  prep_k<<<2304, 256, 0, stream>>>(wq, wk, wv, wu, wo, wb, hidden, ln_w, hb);
  gemm_qkvu_k<<<dim3(256, 4), 256, 0, stream>>>(hb, wb, q, k, vT, u, attn);
  qk_attn_k<<<dim3(36, 32), 256, 0, stream>>>(q, k, ts, ts_w, pos_w, attn);
  pv_k<<<dim3(17, 32), 256, 0, stream>>>(attn, vT, ao0, ao1, ao2);
  gated_k<<<4096, 64, 0, stream>>>(ao0, ao1, ao2, u, attn_ln_w, gated);
  gemm_out_k<<<256, 256, 0, stream>>>(gated, wb + 4 * DIM * DIM, hidden, out);
}

// Round 15
// 104.113 us; speedup vs baseline: 1.0077x; 1.0077x over previous
//
#include <hip/hip_runtime.h>
#include <hip/hip_bf16.h>

typedef __hip_bfloat16 bf16;
typedef __attribute__((ext_vector_type(8))) short short8;
typedef __attribute__((ext_vector_type(4))) float f32x4;

#define SL 1024
#define DIM 512
#define NH 8
#define HD 64
#define NBUCK 128

__device__ __forceinline__ float silu_f(float x) { return x / (1.0f + __expf(-x)); }

__device__ __forceinline__ short f2bf(float x) {
  bf16 b = __float2bfloat16(x);
  return *reinterpret_cast<short*>(&b);
}

__device__ __forceinline__ void gld_lds16(const void* g, void* l) {
  __builtin_amdgcn_global_load_lds(
      (const __attribute__((address_space(1))) void*)g,
      (__attribute__((address_space(3))) void*)l, 16, 0, 0);
}

// ---------- fused prep: weights f32->bf16 (blocks 0..1279) + rmsnorm (blocks 1280..2303) ----------
__global__ __launch_bounds__(256) void prep_k(const float* __restrict__ s0, const float* __restrict__ s1,
                                              const float* __restrict__ s2, const float* __restrict__ s3,
                                              const float* __restrict__ s4, bf16* __restrict__ wdst,
                                              const float* __restrict__ hidden, const float* __restrict__ ln_w,
                                              bf16* __restrict__ hb) {
  int bx = blockIdx.x;
  if (bx < 1280) {
    int wsel = bx >> 8;
    const float* src = wsel == 0 ? s0 : wsel == 1 ? s1 : wsel == 2 ? s2 : wsel == 3 ? s3 : s4;
    int i = ((bx & 255) * 256 + threadIdx.x) * 4;
    float4 v = *(const float4*)(src + i);
    bf16* d = wdst + (size_t)wsel * DIM * DIM + i;
    d[0] = __float2bfloat16(v.x);
    d[1] = __float2bfloat16(v.y);
    d[2] = __float2bfloat16(v.z);
    d[3] = __float2bfloat16(v.w);
  } else {
    int row = (bx - 1280) * 4 + (threadIdx.x >> 6);  // one row per wave
    int l = threadIdx.x & 63;
    const float4* xr = (const float4*)(hidden + (size_t)row * DIM);
    float4 v0 = xr[l], v1 = xr[l + 64];
    float s = v0.x*v0.x + v0.y*v0.y + v0.z*v0.z + v0.w*v0.w
            + v1.x*v1.x + v1.y*v1.y + v1.z*v1.z + v1.w*v1.w;
    #pragma unroll
    for (int o = 32; o; o >>= 1) s += __shfl_xor(s, o);
    float sc = rsqrtf(s * (1.0f / DIM) + 1e-6f);
    bf16* orow = hb + (size_t)row * DIM;
    int c0 = l * 4, c1 = 256 + l * 4;
    orow[c0 + 0] = __float2bfloat16(v0.x * sc * ln_w[c0 + 0]);
    orow[c0 + 1] = __float2bfloat16(v0.y * sc * ln_w[c0 + 1]);
    orow[c0 + 2] = __float2bfloat16(v0.z * sc * ln_w[c0 + 2]);
    orow[c0 + 3] = __float2bfloat16(v0.w * sc * ln_w[c0 + 3]);
    orow[c1 + 0] = __float2bfloat16(v1.x * sc * ln_w[c1 + 0]);
    orow[c1 + 1] = __float2bfloat16(v1.y * sc * ln_w[c1 + 1]);
    orow[c1 + 2] = __float2bfloat16(v1.z * sc * ln_w[c1 + 2]);
    orow[c1 + 3] = __float2bfloat16(v1.w * sc * ln_w[c1 + 3]);
  }
}

// ---------- q,k,u,vT = silu(h @ W^T), 128x64 tiles (one head per tile), BK=64 ----------
// grid (256, 4): bm = x&31 (XCD swizzle), bn = x>>5 (head / 64-col panel), mode = y
__global__ __launch_bounds__(256) void gemm_qkvu_k(const bf16* __restrict__ hb,
                                                   const bf16* __restrict__ wb,
                                                   bf16* __restrict__ q, bf16* __restrict__ k,
                                                   bf16* __restrict__ vT, bf16* __restrict__ u) {
  int mode = blockIdx.y;
  int bm = blockIdx.x & 31, bn = blockIdx.x >> 5;
  int t = threadIdx.x, w = t >> 6, l = t & 63;
  int ln = l & 15, l4 = (l >> 4) * 4;
  __shared__ __align__(16) short lds[12288];  // A [128][64] + B [64][64]; reused 128*65 transpose
  const bf16* wbm = wb + (size_t)mode * DIM * DIM;
  f32x4 acc[2][4];
  #pragma unroll
  for (int m = 0; m < 2; ++m)
    #pragma unroll
    for (int n = 0; n < 4; ++n) { f32x4 z = {0.f, 0.f, 0.f, 0.f}; acc[m][n] = z; }

  int srow8 = l >> 3;
  int scol = ((l & 7) ^ srow8) * 8;
  for (int kt = 0; kt < 8; ++kt) {
    if (kt) __syncthreads();
    #pragma unroll
    for (int i = 0; i < 6; ++i) {
      int s = i * 4 + w;                    // 0..23; 0-15 A (128 rows), 16-23 B (64 rows)
      int row = (s < 16 ? s : s - 16) * 8 + srow8;
      int col = kt * 64 + scol;
      const bf16* g = (s < 16)
          ? (hb + (size_t)(bm * 128 + row) * DIM + col)
          : (wbm + (size_t)(bn * 64 + row) * DIM + col);
      gld_lds16(g, lds + s * 512 + l * 8);
    }
    __syncthreads();
    #pragma unroll
    for (int kk = 0; kk < 2; ++kk) {
      short8 a[2], b[4];
      #pragma unroll
      for (int m = 0; m < 2; ++m) {
        int row = w * 32 + m * 16 + ln;
        int c = ((kk * 4 + (l >> 4)) ^ (row & 7)) * 8;
        a[m] = *(const short8*)(lds + row * 64 + c);
      }
      #pragma unroll
      for (int n = 0; n < 4; ++n) {
        int row = n * 16 + ln;
        int c = ((kk * 4 + (l >> 4)) ^ (row & 7)) * 8;
        b[n] = *(const short8*)(lds + 8192 + row * 64 + c);
      }
      #pragma unroll
      for (int m = 0; m < 2; ++m)
        #pragma unroll
        for (int n = 0; n < 4; ++n)
          acc[m][n] = __builtin_amdgcn_mfma_f32_16x16x32_bf16(a[m], b[n], acc[m][n], 0, 0, 0);
    }
  }

  if (mode == 2) {
    // tile = one head's [128 rows]x[64 d]; transpose via LDS into vT[b,h,d,l]
    __syncthreads();                   // gemm reads done, LDS free
    #pragma unroll
    for (int m = 0; m < 2; ++m)
      #pragma unroll
      for (int n = 0; n < 4; ++n)
        #pragma unroll
        for (int j = 0; j < 4; ++j) {
          int rl = w * 32 + m * 16 + l4 + j;   // 0..127
          int cl = n * 16 + ln;                // 0..63
          lds[rl * 65 + cl] = f2bf(silu_f(acc[m][n][j]));
        }
    __syncthreads();
    int b = bm >> 3, li0 = (bm & 7) * 128;
    int d = t >> 2, seg = t & 3;
    bf16* dst = vT + ((size_t)(b * NH + bn) * HD + d) * SL + li0 + seg * 32;
    short8 y0, y1, y2, y3;
    #pragma unroll
    for (int qq = 0; qq < 8; ++qq) {
      y0[qq] = lds[(seg * 32 + qq) * 65 + d];
      y1[qq] = lds[(seg * 32 + 8 + qq) * 65 + d];
      y2[qq] = lds[(seg * 32 + 16 + qq) * 65 + d];
      y3[qq] = lds[(seg * 32 + 24 + qq) * 65 + d];
    }
    *(short8*)dst = y0; *(short8*)(dst + 8) = y1;
    *(short8*)(dst + 16) = y2; *(short8*)(dst + 24) = y3;
    return;
  }

  #pragma unroll
  for (int m = 0; m < 2; ++m)
    #pragma unroll
    for (int n = 0; n < 4; ++n)
      #pragma unroll
      for (int j = 0; j < 4; ++j) {
        int rg = bm * 128 + w * 32 + m * 16 + l4 + j;
        int c64 = n * 16 + ln;
        bf16 val = __float2bfloat16(silu_f(acc[m][n][j]));
        int b = rg >> 10, li = rg & 1023;
        if (mode == 0)      q[((size_t)(b * NH + bn) * SL + li) * HD + c64] = val;
        else if (mode == 1) k[((size_t)(b * NH + bn) * SL + li) * HD + c64] = val;
        else                u[(size_t)rg * DIM + bn * 64 + c64] = val;
      }
}

// ---------- attn = silu(q k^T + bias)/L, lower tiles + folded zero tiles ----------
__global__ __launch_bounds__(256) void qk_attn_k(const bf16* __restrict__ q,
                                                 const bf16* __restrict__ k,
                                                 const int* __restrict__ ts,
                                                 const float* __restrict__ ts_w,
                                                 const float* __restrict__ pos_w,
                                                 float* __restrict__ attn) {
  int bh = blockIdx.y, x = blockIdx.x;
  int ti = 0, accx = 0;
  while (accx + ti + 1 <= x) { accx += ti + 1; ++ti; }
  int tj = x - accx;                   // tj <= ti
  int t = threadIdx.x, w = t >> 6, l = t & 63;
  int ln = l & 15, l4 = (l >> 4) * 4;
  int wr = (w >> 1) * 64, wc = (w & 1) * 64;
  float* arow = attn + (size_t)bh * SL * SL;

  __shared__ __align__(16) short lds[16384];  // q tile [128][64], k tile [128][64]
  __shared__ float tw_l[NBUCK + 1];
  __shared__ float pw_l[255];
  __shared__ int tsi_l[128], tsj_l[128];

  const int* tsb = ts + (size_t)(bh >> 3) * SL;
  if (t < NBUCK + 1) tw_l[t] = ts_w[t];
  if (t < 255) pw_l[t] = pos_w[896 + (tj - ti) * 128 + t];
  if (t < 128) tsi_l[t] = tsb[min(ti * 128 + t + 1, SL - 1)];
  else         tsj_l[t - 128] = tsb[tj * 128 + (t - 128)];

  #pragma unroll
  for (int i = 0; i < 8; ++i) {
    int s = i * 4 + w;                 // 0..31; 0-15 q, 16-31 k
    int row = (s & 15) * 8 + (l >> 3);
    int col = ((l & 7) ^ (l >> 3)) * 8;   // pre-swizzled source (row&7 == l>>3)
    const bf16* g = (s < 16)
        ? (q + (size_t)bh * SL * HD + (size_t)(ti * 128 + row) * HD + col)
        : (k + (size_t)bh * SL * HD + (size_t)(tj * 128 + row) * HD + col);
    gld_lds16(g, lds + s * 512 + l * 8);
  }
  __syncthreads();

  f32x4 acc[4][4];
  #pragma unroll
  for (int m = 0; m < 4; ++m)
    #pragma unroll
    for (int n = 0; n < 4; ++n) { f32x4 z = {0.f, 0.f, 0.f, 0.f}; acc[m][n] = z; }
  #pragma unroll
  for (int kk = 0; kk < 2; ++kk) {        // chunk base 0 / 4
    short8 a[4], b[4];
    #pragma unroll
    for (int m = 0; m < 4; ++m) {
      int row = wr + m * 16 + ln;
      int c = ((kk * 4 + (l >> 4)) ^ (row & 7)) * 8;
      a[m] = *(const short8*)(lds + row * 64 + c);
    }
    #pragma unroll
    for (int n = 0; n < 4; ++n) {
      int row = wc + n * 16 + ln;
      int c = ((kk * 4 + (l >> 4)) ^ (row & 7)) * 8;
      b[n] = *(const short8*)(lds + 8192 + row * 64 + c);
    }
    #pragma unroll
    for (int m = 0; m < 4; ++m)
      #pragma unroll
      for (int n = 0; n < 4; ++n)
        acc[m][n] = __builtin_amdgcn_mfma_f32_16x16x32_bf16(a[m], b[n], acc[m][n], 0, 0, 0);
  }

  const float LSC = 2.30281455f;       // ln2 / 0.301
  #pragma unroll
  for (int m = 0; m < 4; ++m)
    #pragma unroll
    for (int j = 0; j < 4; ++j) {
      int il = wr + m * 16 + l4 + j;
      int tsi = tsi_l[il];
      int i = ti * 128 + il;
      #pragma unroll
      for (int n = 0; n < 4; ++n) {
        int jl = wc + n * 16 + ln;
        int jj = tj * 128 + jl;
        float v = acc[m][n][j];
        int dt = tsi - tsj_l[jl];
        float adf = fmaxf(fabsf((float)dt), 1.0f);
        int bucket = (int)(__log2f(adf) * LSC);
        bucket = bucket < 0 ? 0 : (bucket > NBUCK ? NBUCK : bucket);
        float bias = tw_l[bucket] + pw_l[jl - il + 127];
        float o = (jj <= i) ? silu_f(v + bias) * (1.0f / (float)SL) : 0.0f;
        arow[(size_t)i * SL + jj] = o;
      }
    }

  // folded zero-fill of one strict-upper tile (28 tiles over blocks 0..27)
  if (x < 28) {
    int zi = 0, acc2 = 0;
    while (acc2 + (7 - zi) <= x) { acc2 += 7 - zi; ++zi; }
    int zj = zi + 1 + (x - acc2);
    float4 z4 = make_float4(0.f, 0.f, 0.f, 0.f);
    #pragma unroll
    for (int rep = 0; rep < 16; ++rep) {
      int flat = rep * 256 + t;
      int row = flat >> 5, c4 = flat & 31;
      *(float4*)(arow + (size_t)(zi * 128 + row) * SL + zj * 128 + c4 * 4) = z4;
    }
  }
}

// ---------- partial attn_out, balanced chunks (<=6 kt64 units), 3 partial slots ----------
__global__ __launch_bounds__(256) void pv_k(const float* __restrict__ attn,
                                            const bf16* __restrict__ vT,
                                            float* __restrict__ ao0,
                                            float* __restrict__ ao1,
                                            float* __restrict__ ao2) {
  // chunk tables: per bm (0..7) the 2*(bm+1) kt64 units are split into <=3 chunks
  static const char cb_bm[17] = {0,1,2,2,3,3,4,4,5,5,5,6,6,6,7,7,7};
  static const char cb_lo[17] = {0,0,0,3,0,4,0,5,0,4,8,0,5,10,0,6,11};
  static const char cb_hi[17] = {2,4,3,6,4,8,5,10,4,8,12,5,10,14,6,11,16};
  static const char cb_sl[17] = {0,0,0,1,0,1,0,1,0,1,2,0,1,2,0,1,2};
  int ch = blockIdx.x, bh = blockIdx.y;
  int bm = cb_bm[ch], klo = cb_lo[ch], khi = cb_hi[ch], slot = cb_sl[ch];
  int t = threadIdx.x, w = t >> 6, l = t & 63;
  int ln = l & 15, l4 = (l >> 4) * 4;
  __shared__ __align__(16) short lds[12288];  // A [128][64] + B [64][64]
  const float* arow = attn + (size_t)bh * SL * SL;
  const bf16* vrow = vT + (size_t)bh * HD * SL;
  f32x4 acc[2][4];
  #pragma unroll
  for (int m = 0; m < 2; ++m)
    #pragma unroll
    for (int n = 0; n < 4; ++n) { f32x4 z = {0.f, 0.f, 0.f, 0.f}; acc[m][n] = z; }

  int srow8 = l >> 3;
  int swc = ((l & 7) ^ srow8) * 8;          // swizzled chunk (row&7 == l>>3)
  for (int kt = klo; kt < khi; ++kt) {
    if (kt > klo) __syncthreads();
    // A tile: 16 slices (4/wave) from f32 attn, reg-converted to bf16, swizzled ds_write
    #pragma unroll
    for (int ss = 0; ss < 4; ++ss) {
      int s = w * 4 + ss;                   // 0..15
      int row = s * 8 + srow8;              // 0..127
      const float* g = arow + (size_t)(bm * 128 + row) * SL + kt * 64 + (l & 7) * 8;
      float4 f0 = *(const float4*)g;
      float4 f1 = *(const float4*)(g + 4);
      short8 vv;
      vv[0] = f2bf(f0.x); vv[1] = f2bf(f0.y); vv[2] = f2bf(f0.z); vv[3] = f2bf(f0.w);
      vv[4] = f2bf(f1.x); vv[5] = f2bf(f1.y); vv[6] = f2bf(f1.z); vv[7] = f2bf(f1.w);
      *(short8*)(lds + row * 64 + swc) = vv;
    }
    // B tile: 8 slices (2/wave) from bf16 vT via async LDS, pre-swizzled source
    #pragma unroll
    for (int i = 0; i < 2; ++i) {
      int s2 = i * 4 + w;                   // 0..7
      int row = s2 * 8 + srow8;             // 0..63
      gld_lds16(vrow + (size_t)row * SL + kt * 64 + swc, lds + 8192 + s2 * 512 + l * 8);
    }
    __syncthreads();
    #pragma unroll
    for (int kk = 0; kk < 2; ++kk) {
      short8 a[2], b[4];
      #pragma unroll
      for (int m = 0; m < 2; ++m) {
        int row = w * 32 + m * 16 + ln;
        int c = ((kk * 4 + (l >> 4)) ^ (row & 7)) * 8;
        a[m] = *(const short8*)(lds + row * 64 + c);
      }
      #pragma unroll
      for (int n = 0; n < 4; ++n) {
        int row = n * 16 + ln;
        int c = ((kk * 4 + (l >> 4)) ^ (row & 7)) * 8;
        b[n] = *(const short8*)(lds + 8192 + row * 64 + c);
      }
      #pragma unroll
      for (int m = 0; m < 2; ++m)
        #pragma unroll
        for (int n = 0; n < 4; ++n)
          acc[m][n] = __builtin_amdgcn_mfma_f32_16x16x32_bf16(a[m], b[n], acc[m][n], 0, 0, 0);
    }
  }

  float* aop = slot == 0 ? ao0 : (slot == 1 ? ao1 : ao2);
  int b = bh >> 3, hh = bh & 7;
  #pragma unroll
  for (int m = 0; m < 2; ++m)
    #pragma unroll
    for (int n = 0; n < 4; ++n)
      #pragma unroll
      for (int j = 0; j < 4; ++j) {
        int i = bm * 128 + w * 32 + m * 16 + l4 + j;
        int dd = n * 16 + ln;
        aop[((size_t)(b * SL + i)) * DIM + hh * HD + dd] = acc[m][n][j];
      }
}

// ---------- gated = u * rmsnorm(sum of partials) * attn_ln_w ----------
// partial count per 128-row band: {1,1,2,2,2,3,3,3}
__global__ void gated_k(const float* __restrict__ ao0, const float* __restrict__ ao1,
                        const float* __restrict__ ao2, const bf16* __restrict__ u,
                        const float* __restrict__ w, bf16* __restrict__ g) {
  int row = blockIdx.x, l = threadIdx.x;  // 64 threads
  int bmRow = (row & 1023) >> 7;
  const float4* ar0 = (const float4*)(ao0 + (size_t)row * DIM);
  const float4* ar1 = (const float4*)(ao1 + (size_t)row * DIM);
  const float4* ar2 = (const float4*)(ao2 + (size_t)row * DIM);
  float4 a0 = ar0[l], a1 = ar0[l + 64];
  if (bmRow >= 2) {
    float4 p0 = ar1[l], p1 = ar1[l + 64];
    a0.x += p0.x; a0.y += p0.y; a0.z += p0.z; a0.w += p0.w;
    a1.x += p1.x; a1.y += p1.y; a1.z += p1.z; a1.w += p1.w;
  }
  if (bmRow >= 5) {
    float4 p0 = ar2[l], p1 = ar2[l + 64];
    a0.x += p0.x; a0.y += p0.y; a0.z += p0.z; a0.w += p0.w;
    a1.x += p1.x; a1.y += p1.y; a1.z += p1.z; a1.w += p1.w;
  }
  float s = a0.x*a0.x + a0.y*a0.y + a0.z*a0.z + a0.w*a0.w
          + a1.x*a1.x + a1.y*a1.y + a1.z*a1.z + a1.w*a1.w;
  #pragma unroll
  for (int o = 32; o; o >>= 1) s += __shfl_xor(s, o);
  float sc = rsqrtf(s * (1.0f / DIM) + 1e-6f);
  const bf16* ur = u + (size_t)row * DIM;
  bf16* gr = g + (size_t)row * DIM;
  int c0 = l * 4, c1 = 256 + l * 4;
  gr[c0 + 0] = __float2bfloat16(__bfloat162float(ur[c0 + 0]) * a0.x * sc * w[c0 + 0]);
  gr[c0 + 1] = __float2bfloat16(__bfloat162float(ur[c0 + 1]) * a0.y * sc * w[c0 + 1]);
  gr[c0 + 2] = __float2bfloat16(__bfloat162float(ur[c0 + 2]) * a0.z * sc * w[c0 + 2]);
  gr[c0 + 3] = __float2bfloat16(__bfloat162float(ur[c0 + 3]) * a0.w * sc * w[c0 + 3]);
  gr[c1 + 0] = __float2bfloat16(__bfloat162float(ur[c1 + 0]) * a1.x * sc * w[c1 + 0]);
  gr[c1 + 1] = __float2bfloat16(__bfloat162float(ur[c1 + 1]) * a1.y * sc * w[c1 + 1]);
  gr[c1 + 2] = __float2bfloat16(__bfloat162float(ur[c1 + 2]) * a1.z * sc * w[c1 + 2]);
  gr[c1 + 3] = __float2bfloat16(__bfloat162float(ur[c1 + 3]) * a1.w * sc * w[c1 + 3]);
}

// ---------- out = residual + gated @ wo^T, 128x64 tiles, BK=64, XCD-swizzled ----------
__global__ __launch_bounds__(256) void gemm_out_k(const bf16* __restrict__ gated,
                                                  const bf16* __restrict__ wob,
                                                  const float* __restrict__ residual,
                                                  float* __restrict__ out) {
  int bm = blockIdx.x & 31, bn = blockIdx.x >> 5;
  int t = threadIdx.x, w = t >> 6, l = t & 63;
  int ln = l & 15, l4 = (l >> 4) * 4;
  __shared__ __align__(16) short lds[12288];  // A [128][64] + B [64][64]
  f32x4 acc[2][4];
  #pragma unroll
  for (int m = 0; m < 2; ++m)
    #pragma unroll
    for (int n = 0; n < 4; ++n) { f32x4 z = {0.f, 0.f, 0.f, 0.f}; acc[m][n] = z; }

  int srow8 = l >> 3;
  int scol = ((l & 7) ^ srow8) * 8;
  for (int kt = 0; kt < 8; ++kt) {
    if (kt) __syncthreads();
    #pragma unroll
    for (int i = 0; i < 6; ++i) {
      int s = i * 4 + w;                    // 0..23; 0-15 A (128 rows), 16-23 B (64 rows)
      int row = (s < 16 ? s : s - 16) * 8 + srow8;
      int col = kt * 64 + scol;
      const bf16* g = (s < 16)
          ? (gated + (size_t)(bm * 128 + row) * DIM + col)
          : (wob + (size_t)(bn * 64 + row) * DIM + col);
      gld_lds16(g, lds + s * 512 + l * 8);
    }
    __syncthreads();
    #pragma unroll
    for (int kk = 0; kk < 2; ++kk) {
      short8 a[2], b[4];
      #pragma unroll
      for (int m = 0; m < 2; ++m) {
        int row = w * 32 + m * 16 + ln;
        int c = ((kk * 4 + (l >> 4)) ^ (row & 7)) * 8;
        a[m] = *(const short8*)(lds + row * 64 + c);
      }
      #pragma unroll
      for (int n = 0; n < 4; ++n) {
        int row = n * 16 + ln;
        int c = ((kk * 4 + (l >> 4)) ^ (row & 7)) * 8;
        b[n] = *(const short8*)(lds + 8192 + row * 64 + c);
      }
      #pragma unroll
      for (int m = 0; m < 2; ++m)
        #pragma unroll
        for (int n = 0; n < 4; ++n)
          acc[m][n] = __builtin_amdgcn_mfma_f32_16x16x32_bf16(a[m], b[n], acc[m][n], 0, 0, 0);
    }
  }

  #pragma unroll
  for (int m = 0; m < 2; ++m)
    #pragma unroll
    for (int n = 0; n < 4; ++n)
      #pragma unroll
      for (int j = 0; j < 4; ++j) {
        int rg = bm * 128 + w * 32 + m * 16 + l4 + j;
        int cg = bn * 64 + n * 16 + ln;
        size_t idx = (size_t)rg * DIM + cg;
        out[idx] = acc[m][n][j] + residual[idx];
      }
}

extern "C" void kernel_launch(void* const* d_in, const int* in_sizes, int n_in,
                              void* d_out, int out_size, void* d_ws, size_t ws_size,
                              hipStream_t stream) {
  const float* hidden    = (const float*)d_in[0];
  // d_in[1] = attention_mask (causal tril) — recomputed analytically
  const int*   ts        = (const int*)d_in[2];
  const float* ln_w      = (const float*)d_in[3];
  const float* attn_ln_w = (const float*)d_in[4];
  const float* wq        = (const float*)d_in[5];
  const float* wk        = (const float*)d_in[6];
  const float* wv        = (const float*)d_in[7];
  const float* wu        = (const float*)d_in[8];
  const float* wo        = (const float*)d_in[9];
  const float* ts_w      = (const float*)d_in[10];
  const float* pos_w     = (const float*)d_in[11];

  // OUTPUTS ARE FLOAT32: out [4,1024,512] then attn [4,8,1024,1024]
  float* out  = (float*)d_out;
  float* attn = out + 2097152;

  // workspace (~44.6 MiB < proven 56 MiB); ao2 overlays hb+q (dead by pv time)
  bf16* wb    = (bf16*)d_ws;           // 5 * 512*512
  bf16* hb    = wb + 5 * DIM * DIM;    // [4096,512]
  bf16* q     = hb + 2097152;          // [b,h,l,d]
  bf16* k     = q + 2097152;
  bf16* vT    = k + 2097152;           // [b,h,d,l] (written directly by gemm_qkvu)
  bf16* u     = vT + 2097152;          // [4096,512]
  bf16* gated = u + 2097152;           // [4096,512]
  float* ao0  = (float*)(gated + 2097152);  // [4096,512] f32
  float* ao1  = ao0 + 2097152;              // [4096,512] f32
  float* ao2  = (float*)hb;                 // overlay: hb(4MB)+q(4MB) dead after qk_attn

  prep_k<<<2304, 256, 0, stream>>>(wq, wk, wv, wu, wo, wb, hidden, ln_w, hb);
  gemm_qkvu_k<<<dim3(256, 4), 256, 0, stream>>>(hb, wb, q, k, vT, u);
  qk_attn_k<<<dim3(36, 32), 256, 0, stream>>>(q, k, ts, ts_w, pos_w, attn);
  pv_k<<<dim3(17, 32), 256, 0, stream>>>(attn, vT, ao0, ao1, ao2);
  gated_k<<<4096, 64, 0, stream>>>(ao0, ao1, ao2, u, attn_ln_w, gated);
  gemm_out_k<<<256, 256, 0, stream>>>(gated, wb + 4 * DIM * DIM, hidden, out);
}

// Round 16
// 101.060 us; speedup vs baseline: 1.0381x; 1.0302x over previous
//
#include <hip/hip_runtime.h>
#include <hip/hip_bf16.h>

typedef __hip_bfloat16 bf16;
typedef __attribute__((ext_vector_type(8))) short short8;
typedef __attribute__((ext_vector_type(4))) float f32x4;

#define SL 1024
#define DIM 512
#define NH 8
#define HD 64
#define NBUCK 128

__device__ __forceinline__ float silu_f(float x) { return x / (1.0f + __expf(-x)); }

__device__ __forceinline__ short f2bf(float x) {
  bf16 b = __float2bfloat16(x);
  return *reinterpret_cast<short*>(&b);
}

__device__ __forceinline__ float bf2f(short s) {
  bf16 b = *reinterpret_cast<bf16*>(&s);
  return __bfloat162float(b);
}

__device__ __forceinline__ void gld_lds16(const void* g, void* l) {
  __builtin_amdgcn_global_load_lds(
      (const __attribute__((address_space(1))) void*)g,
      (__attribute__((address_space(3))) void*)l, 16, 0, 0);
}

// ---------- fused prep: weights f32->bf16 (blocks 0..1279) + rmsnorm (blocks 1280..2303) ----------
__global__ __launch_bounds__(256) void prep_k(const float* __restrict__ s0, const float* __restrict__ s1,
                                              const float* __restrict__ s2, const float* __restrict__ s3,
                                              const float* __restrict__ s4, bf16* __restrict__ wdst,
                                              const float* __restrict__ hidden, const float* __restrict__ ln_w,
                                              bf16* __restrict__ hb) {
  int bx = blockIdx.x;
  if (bx < 1280) {
    int wsel = bx >> 8;
    const float* src = wsel == 0 ? s0 : wsel == 1 ? s1 : wsel == 2 ? s2 : wsel == 3 ? s3 : s4;
    int i = ((bx & 255) * 256 + threadIdx.x) * 4;
    float4 v = *(const float4*)(src + i);
    bf16* d = wdst + (size_t)wsel * DIM * DIM + i;
    d[0] = __float2bfloat16(v.x);
    d[1] = __float2bfloat16(v.y);
    d[2] = __float2bfloat16(v.z);
    d[3] = __float2bfloat16(v.w);
  } else {
    int row = (bx - 1280) * 4 + (threadIdx.x >> 6);  // one row per wave
    int l = threadIdx.x & 63;
    const float4* xr = (const float4*)(hidden + (size_t)row * DIM);
    float4 v0 = xr[l], v1 = xr[l + 64];
    float s = v0.x*v0.x + v0.y*v0.y + v0.z*v0.z + v0.w*v0.w
            + v1.x*v1.x + v1.y*v1.y + v1.z*v1.z + v1.w*v1.w;
    #pragma unroll
    for (int o = 32; o; o >>= 1) s += __shfl_xor(s, o);
    float sc = rsqrtf(s * (1.0f / DIM) + 1e-6f);
    bf16* orow = hb + (size_t)row * DIM;
    int c0 = l * 4, c1 = 256 + l * 4;
    orow[c0 + 0] = __float2bfloat16(v0.x * sc * ln_w[c0 + 0]);
    orow[c0 + 1] = __float2bfloat16(v0.y * sc * ln_w[c0 + 1]);
    orow[c0 + 2] = __float2bfloat16(v0.z * sc * ln_w[c0 + 2]);
    orow[c0 + 3] = __float2bfloat16(v0.w * sc * ln_w[c0 + 3]);
    orow[c1 + 0] = __float2bfloat16(v1.x * sc * ln_w[c1 + 0]);
    orow[c1 + 1] = __float2bfloat16(v1.y * sc * ln_w[c1 + 1]);
    orow[c1 + 2] = __float2bfloat16(v1.z * sc * ln_w[c1 + 2]);
    orow[c1 + 3] = __float2bfloat16(v1.w * sc * ln_w[c1 + 3]);
  }
}

// ---------- q,k,u,vT = silu(h @ W^T), 128x64 tiles (one head per tile), BK=64 ----------
// grid (256, 4): bm = x&31 (XCD swizzle), bn = x>>5 (head / 64-col panel), mode = y
__global__ __launch_bounds__(256) void gemm_qkvu_k(const bf16* __restrict__ hb,
                                                   const bf16* __restrict__ wb,
                                                   bf16* __restrict__ q, bf16* __restrict__ k,
                                                   bf16* __restrict__ vT, bf16* __restrict__ u) {
  int mode = blockIdx.y;
  int bm = blockIdx.x & 31, bn = blockIdx.x >> 5;
  int t = threadIdx.x, w = t >> 6, l = t & 63;
  int ln = l & 15, l4 = (l >> 4) * 4;
  __shared__ __align__(16) short lds[12288];  // A [128][64] + B [64][64]; reused 128*65 transpose
  const bf16* wbm = wb + (size_t)mode * DIM * DIM;
  f32x4 acc[2][4];
  #pragma unroll
  for (int m = 0; m < 2; ++m)
    #pragma unroll
    for (int n = 0; n < 4; ++n) { f32x4 z = {0.f, 0.f, 0.f, 0.f}; acc[m][n] = z; }

  int srow8 = l >> 3;
  int scol = ((l & 7) ^ srow8) * 8;
  for (int kt = 0; kt < 8; ++kt) {
    if (kt) __syncthreads();
    #pragma unroll
    for (int i = 0; i < 6; ++i) {
      int s = i * 4 + w;                    // 0..23; 0-15 A (128 rows), 16-23 B (64 rows)
      int row = (s < 16 ? s : s - 16) * 8 + srow8;
      int col = kt * 64 + scol;
      const bf16* g = (s < 16)
          ? (hb + (size_t)(bm * 128 + row) * DIM + col)
          : (wbm + (size_t)(bn * 64 + row) * DIM + col);
      gld_lds16(g, lds + s * 512 + l * 8);
    }
    __syncthreads();
    #pragma unroll
    for (int kk = 0; kk < 2; ++kk) {
      short8 a[2], b[4];
      #pragma unroll
      for (int m = 0; m < 2; ++m) {
        int row = w * 32 + m * 16 + ln;
        int c = ((kk * 4 + (l >> 4)) ^ (row & 7)) * 8;
        a[m] = *(const short8*)(lds + row * 64 + c);
      }
      #pragma unroll
      for (int n = 0; n < 4; ++n) {
        int row = n * 16 + ln;
        int c = ((kk * 4 + (l >> 4)) ^ (row & 7)) * 8;
        b[n] = *(const short8*)(lds + 8192 + row * 64 + c);
      }
      #pragma unroll
      for (int m = 0; m < 2; ++m)
        #pragma unroll
        for (int n = 0; n < 4; ++n)
          acc[m][n] = __builtin_amdgcn_mfma_f32_16x16x32_bf16(a[m], b[n], acc[m][n], 0, 0, 0);
    }
  }

  if (mode == 2) {
    // tile = one head's [128 rows]x[64 d]; transpose via LDS into vT[b,h,d,l]
    __syncthreads();                   // gemm reads done, LDS free
    #pragma unroll
    for (int m = 0; m < 2; ++m)
      #pragma unroll
      for (int n = 0; n < 4; ++n)
        #pragma unroll
        for (int j = 0; j < 4; ++j) {
          int rl = w * 32 + m * 16 + l4 + j;   // 0..127
          int cl = n * 16 + ln;                // 0..63
          lds[rl * 65 + cl] = f2bf(silu_f(acc[m][n][j]));
        }
    __syncthreads();
    int b = bm >> 3, li0 = (bm & 7) * 128;
    int d = t >> 2, seg = t & 3;
    bf16* dst = vT + ((size_t)(b * NH + bn) * HD + d) * SL + li0 + seg * 32;
    short8 y0, y1, y2, y3;
    #pragma unroll
    for (int qq = 0; qq < 8; ++qq) {
      y0[qq] = lds[(seg * 32 + qq) * 65 + d];
      y1[qq] = lds[(seg * 32 + 8 + qq) * 65 + d];
      y2[qq] = lds[(seg * 32 + 16 + qq) * 65 + d];
      y3[qq] = lds[(seg * 32 + 24 + qq) * 65 + d];
    }
    *(short8*)dst = y0; *(short8*)(dst + 8) = y1;
    *(short8*)(dst + 16) = y2; *(short8*)(dst + 24) = y3;
    return;
  }

  #pragma unroll
  for (int m = 0; m < 2; ++m)
    #pragma unroll
    for (int n = 0; n < 4; ++n)
      #pragma unroll
      for (int j = 0; j < 4; ++j) {
        int rg = bm * 128 + w * 32 + m * 16 + l4 + j;
        int c64 = n * 16 + ln;
        bf16 val = __float2bfloat16(silu_f(acc[m][n][j]));
        int b = rg >> 10, li = rg & 1023;
        if (mode == 0)      q[((size_t)(b * NH + bn) * SL + li) * HD + c64] = val;
        else if (mode == 1) k[((size_t)(b * NH + bn) * SL + li) * HD + c64] = val;
        else                u[(size_t)rg * DIM + bn * 64 + c64] = val;
      }
}

// ---------- attn = silu(q k^T + bias)/L, lower tiles + folded zero tiles ----------
__global__ __launch_bounds__(256) void qk_attn_k(const bf16* __restrict__ q,
                                                 const bf16* __restrict__ k,
                                                 const int* __restrict__ ts,
                                                 const float* __restrict__ ts_w,
                                                 const float* __restrict__ pos_w,
                                                 float* __restrict__ attn) {
  int bh = blockIdx.y, x = blockIdx.x;
  int ti = 0, accx = 0;
  while (accx + ti + 1 <= x) { accx += ti + 1; ++ti; }
  int tj = x - accx;                   // tj <= ti
  int t = threadIdx.x, w = t >> 6, l = t & 63;
  int ln = l & 15, l4 = (l >> 4) * 4;
  int wr = (w >> 1) * 64, wc = (w & 1) * 64;
  float* arow = attn + (size_t)bh * SL * SL;

  __shared__ __align__(16) short lds[16384];  // q tile [128][64], k tile [128][64]
  __shared__ float tw_l[NBUCK + 1];
  __shared__ float pw_l[255];
  __shared__ int tsi_l[128], tsj_l[128];

  const int* tsb = ts + (size_t)(bh >> 3) * SL;
  if (t < NBUCK + 1) tw_l[t] = ts_w[t];
  if (t < 255) pw_l[t] = pos_w[896 + (tj - ti) * 128 + t];
  if (t < 128) tsi_l[t] = tsb[min(ti * 128 + t + 1, SL - 1)];
  else         tsj_l[t - 128] = tsb[tj * 128 + (t - 128)];

  #pragma unroll
  for (int i = 0; i < 8; ++i) {
    int s = i * 4 + w;                 // 0..31; 0-15 q, 16-31 k
    int row = (s & 15) * 8 + (l >> 3);
    int col = ((l & 7) ^ (l >> 3)) * 8;   // pre-swizzled source (row&7 == l>>3)
    const bf16* g = (s < 16)
        ? (q + (size_t)bh * SL * HD + (size_t)(ti * 128 + row) * HD + col)
        : (k + (size_t)bh * SL * HD + (size_t)(tj * 128 + row) * HD + col);
    gld_lds16(g, lds + s * 512 + l * 8);
  }
  __syncthreads();

  f32x4 acc[4][4];
  #pragma unroll
  for (int m = 0; m < 4; ++m)
    #pragma unroll
    for (int n = 0; n < 4; ++n) { f32x4 z = {0.f, 0.f, 0.f, 0.f}; acc[m][n] = z; }
  #pragma unroll
  for (int kk = 0; kk < 2; ++kk) {        // chunk base 0 / 4
    short8 a[4], b[4];
    #pragma unroll
    for (int m = 0; m < 4; ++m) {
      int row = wr + m * 16 + ln;
      int c = ((kk * 4 + (l >> 4)) ^ (row & 7)) * 8;
      a[m] = *(const short8*)(lds + row * 64 + c);
    }
    #pragma unroll
    for (int n = 0; n < 4; ++n) {
      int row = wc + n * 16 + ln;
      int c = ((kk * 4 + (l >> 4)) ^ (row & 7)) * 8;
      b[n] = *(const short8*)(lds + 8192 + row * 64 + c);
    }
    #pragma unroll
    for (int m = 0; m < 4; ++m)
      #pragma unroll
      for (int n = 0; n < 4; ++n)
        acc[m][n] = __builtin_amdgcn_mfma_f32_16x16x32_bf16(a[m], b[n], acc[m][n], 0, 0, 0);
  }

  const float LSC = 2.30281455f;       // ln2 / 0.301
  #pragma unroll
  for (int m = 0; m < 4; ++m)
    #pragma unroll
    for (int j = 0; j < 4; ++j) {
      int il = wr + m * 16 + l4 + j;
      int tsi = tsi_l[il];
      int i = ti * 128 + il;
      #pragma unroll
      for (int n = 0; n < 4; ++n) {
        int jl = wc + n * 16 + ln;
        int jj = tj * 128 + jl;
        float v = acc[m][n][j];
        int dt = tsi - tsj_l[jl];
        float adf = fmaxf(fabsf((float)dt), 1.0f);
        int bucket = (int)(__log2f(adf) * LSC);
        bucket = bucket < 0 ? 0 : (bucket > NBUCK ? NBUCK : bucket);
        float bias = tw_l[bucket] + pw_l[jl - il + 127];
        float o = (jj <= i) ? silu_f(v + bias) * (1.0f / (float)SL) : 0.0f;
        arow[(size_t)i * SL + jj] = o;
      }
    }

  // folded zero-fill of one strict-upper tile (28 tiles over blocks 0..27)
  if (x < 28) {
    int zi = 0, acc2 = 0;
    while (acc2 + (7 - zi) <= x) { acc2 += 7 - zi; ++zi; }
    int zj = zi + 1 + (x - acc2);
    float4 z4 = make_float4(0.f, 0.f, 0.f, 0.f);
    #pragma unroll
    for (int rep = 0; rep < 16; ++rep) {
      int flat = rep * 256 + t;
      int row = flat >> 5, c4 = flat & 31;
      *(float4*)(arow + (size_t)(zi * 128 + row) * SL + zj * 128 + c4 * 4) = z4;
    }
  }
}

// ---------- partial attn_out (bf16 partials), balanced chunks, 3 slots ----------
__global__ __launch_bounds__(256) void pv_k(const float* __restrict__ attn,
                                            const bf16* __restrict__ vT,
                                            bf16* __restrict__ ao0,
                                            bf16* __restrict__ ao1,
                                            bf16* __restrict__ ao2) {
  // chunk tables: per bm (0..7) the 2*(bm+1) kt64 units are split into <=3 chunks
  static const char cb_bm[17] = {0,1,2,2,3,3,4,4,5,5,5,6,6,6,7,7,7};
  static const char cb_lo[17] = {0,0,0,3,0,4,0,5,0,4,8,0,5,10,0,6,11};
  static const char cb_hi[17] = {2,4,3,6,4,8,5,10,4,8,12,5,10,14,6,11,16};
  static const char cb_sl[17] = {0,0,0,1,0,1,0,1,0,1,2,0,1,2,0,1,2};
  int ch = blockIdx.x, bh = blockIdx.y;
  int bm = cb_bm[ch], klo = cb_lo[ch], khi = cb_hi[ch], slot = cb_sl[ch];
  int t = threadIdx.x, w = t >> 6, l = t & 63;
  int ln = l & 15, l4 = (l >> 4) * 4;
  __shared__ __align__(16) short lds[12288];  // A [128][64] + B [64][64]
  const float* arow = attn + (size_t)bh * SL * SL;
  const bf16* vrow = vT + (size_t)bh * HD * SL;
  f32x4 acc[2][4];
  #pragma unroll
  for (int m = 0; m < 2; ++m)
    #pragma unroll
    for (int n = 0; n < 4; ++n) { f32x4 z = {0.f, 0.f, 0.f, 0.f}; acc[m][n] = z; }

  int srow8 = l >> 3;
  int swc = ((l & 7) ^ srow8) * 8;          // swizzled chunk (row&7 == l>>3)
  for (int kt = klo; kt < khi; ++kt) {
    if (kt > klo) __syncthreads();
    // A tile: 16 slices (4/wave) from f32 attn, reg-converted to bf16, swizzled ds_write
    #pragma unroll
    for (int ss = 0; ss < 4; ++ss) {
      int s = w * 4 + ss;                   // 0..15
      int row = s * 8 + srow8;              // 0..127
      const float* g = arow + (size_t)(bm * 128 + row) * SL + kt * 64 + (l & 7) * 8;
      float4 f0 = *(const float4*)g;
      float4 f1 = *(const float4*)(g + 4);
      short8 vv;
      vv[0] = f2bf(f0.x); vv[1] = f2bf(f0.y); vv[2] = f2bf(f0.z); vv[3] = f2bf(f0.w);
      vv[4] = f2bf(f1.x); vv[5] = f2bf(f1.y); vv[6] = f2bf(f1.z); vv[7] = f2bf(f1.w);
      *(short8*)(lds + row * 64 + swc) = vv;
    }
    // B tile: 8 slices (2/wave) from bf16 vT via async LDS, pre-swizzled source
    #pragma unroll
    for (int i = 0; i < 2; ++i) {
      int s2 = i * 4 + w;                   // 0..7
      int row = s2 * 8 + srow8;             // 0..63
      gld_lds16(vrow + (size_t)row * SL + kt * 64 + swc, lds + 8192 + s2 * 512 + l * 8);
    }
    __syncthreads();
    #pragma unroll
    for (int kk = 0; kk < 2; ++kk) {
      short8 a[2], b[4];
      #pragma unroll
      for (int m = 0; m < 2; ++m) {
        int row = w * 32 + m * 16 + ln;
        int c = ((kk * 4 + (l >> 4)) ^ (row & 7)) * 8;
        a[m] = *(const short8*)(lds + row * 64 + c);
      }
      #pragma unroll
      for (int n = 0; n < 4; ++n) {
        int row = n * 16 + ln;
        int c = ((kk * 4 + (l >> 4)) ^ (row & 7)) * 8;
        b[n] = *(const short8*)(lds + 8192 + row * 64 + c);
      }
      #pragma unroll
      for (int m = 0; m < 2; ++m)
        #pragma unroll
        for (int n = 0; n < 4; ++n)
          acc[m][n] = __builtin_amdgcn_mfma_f32_16x16x32_bf16(a[m], b[n], acc[m][n], 0, 0, 0);
    }
  }

  bf16* aop = slot == 0 ? ao0 : (slot == 1 ? ao1 : ao2);
  int b = bh >> 3, hh = bh & 7;
  #pragma unroll
  for (int m = 0; m < 2; ++m)
    #pragma unroll
    for (int n = 0; n < 4; ++n)
      #pragma unroll
      for (int j = 0; j < 4; ++j) {
        int i = bm * 128 + w * 32 + m * 16 + l4 + j;
        int dd = n * 16 + ln;
        aop[((size_t)(b * SL + i)) * DIM + hh * HD + dd] = __float2bfloat16(acc[m][n][j]);
      }
}

// ---------- gated = u * rmsnorm(sum of bf16 partials) * attn_ln_w ----------
// partial count per 128-row band: {1,1,2,2,2,3,3,3}
__global__ void gated_k(const bf16* __restrict__ ao0, const bf16* __restrict__ ao1,
                        const bf16* __restrict__ ao2, const bf16* __restrict__ u,
                        const float* __restrict__ w, bf16* __restrict__ g) {
  int row = blockIdx.x, l = threadIdx.x;  // 64 threads, 8 elems each
  int bmRow = (row & 1023) >> 7;
  int c = l * 8;
  float v[8];
  short8 p0 = *(const short8*)(ao0 + (size_t)row * DIM + c);
  #pragma unroll
  for (int i = 0; i < 8; ++i) v[i] = bf2f(p0[i]);
  if (bmRow >= 2) {
    short8 p1 = *(const short8*)(ao1 + (size_t)row * DIM + c);
    #pragma unroll
    for (int i = 0; i < 8; ++i) v[i] += bf2f(p1[i]);
  }
  if (bmRow >= 5) {
    short8 p2 = *(const short8*)(ao2 + (size_t)row * DIM + c);
    #pragma unroll
    for (int i = 0; i < 8; ++i) v[i] += bf2f(p2[i]);
  }
  float s = 0.0f;
  #pragma unroll
  for (int i = 0; i < 8; ++i) s += v[i] * v[i];
  #pragma unroll
  for (int o = 32; o; o >>= 1) s += __shfl_xor(s, o);
  float sc = rsqrtf(s * (1.0f / DIM) + 1e-6f);
  short8 uu = *(const short8*)(u + (size_t)row * DIM + c);
  short8 gv;
  #pragma unroll
  for (int i = 0; i < 8; ++i)
    gv[i] = f2bf(bf2f(uu[i]) * v[i] * sc * w[c + i]);
  *(short8*)((bf16*)g + (size_t)row * DIM + c) = gv;
}

// ---------- out = residual + gated @ wo^T, 128x64 tiles, BK=64, XCD-swizzled ----------
__global__ __launch_bounds__(256) void gemm_out_k(const bf16* __restrict__ gated,
                                                  const bf16* __restrict__ wob,
                                                  const float* __restrict__ residual,
                                                  float* __restrict__ out) {
  int bm = blockIdx.x & 31, bn = blockIdx.x >> 5;
  int t = threadIdx.x, w = t >> 6, l = t & 63;
  int ln = l & 15, l4 = (l >> 4) * 4;
  __shared__ __align__(16) short lds[12288];  // A [128][64] + B [64][64]
  f32x4 acc[2][4];
  #pragma unroll
  for (int m = 0; m < 2; ++m)
    #pragma unroll
    for (int n = 0; n < 4; ++n) { f32x4 z = {0.f, 0.f, 0.f, 0.f}; acc[m][n] = z; }

  int srow8 = l >> 3;
  int scol = ((l & 7) ^ srow8) * 8;
  for (int kt = 0; kt < 8; ++kt) {
    if (kt) __syncthreads();
    #pragma unroll
    for (int i = 0; i < 6; ++i) {
      int s = i * 4 + w;                    // 0..23; 0-15 A (128 rows), 16-23 B (64 rows)
      int row = (s < 16 ? s : s - 16) * 8 + srow8;
      int col = kt * 64 + scol;
      const bf16* g = (s < 16)
          ? (gated + (size_t)(bm * 128 + row) * DIM + col)
          : (wob + (size_t)(bn * 64 + row) * DIM + col);
      gld_lds16(g, lds + s * 512 + l * 8);
    }
    __syncthreads();
    #pragma unroll
    for (int kk = 0; kk < 2; ++kk) {
      short8 a[2], b[4];
      #pragma unroll
      for (int m = 0; m < 2; ++m) {
        int row = w * 32 + m * 16 + ln;
        int c = ((kk * 4 + (l >> 4)) ^ (row & 7)) * 8;
        a[m] = *(const short8*)(lds + row * 64 + c);
      }
      #pragma unroll
      for (int n = 0; n < 4; ++n) {
        int row = n * 16 + ln;
        int c = ((kk * 4 + (l >> 4)) ^ (row & 7)) * 8;
        b[n] = *(const short8*)(lds + 8192 + row * 64 + c);
      }
      #pragma unroll
      for (int m = 0; m < 2; ++m)
        #pragma unroll
        for (int n = 0; n < 4; ++n)
          acc[m][n] = __builtin_amdgcn_mfma_f32_16x16x32_bf16(a[m], b[n], acc[m][n], 0, 0, 0);
    }
  }

  #pragma unroll
  for (int m = 0; m < 2; ++m)
    #pragma unroll
    for (int n = 0; n < 4; ++n)
      #pragma unroll
      for (int j = 0; j < 4; ++j) {
        int rg = bm * 128 + w * 32 + m * 16 + l4 + j;
        int cg = bn * 64 + n * 16 + ln;
        size_t idx = (size_t)rg * DIM + cg;
        out[idx] = acc[m][n][j] + residual[idx];
      }
}

extern "C" void kernel_launch(void* const* d_in, const int* in_sizes, int n_in,
                              void* d_out, int out_size, void* d_ws, size_t ws_size,
                              hipStream_t stream) {
  const float* hidden    = (const float*)d_in[0];
  // d_in[1] = attention_mask (causal tril) — recomputed analytically
  const int*   ts        = (const int*)d_in[2];
  const float* ln_w      = (const float*)d_in[3];
  const float* attn_ln_w = (const float*)d_in[4];
  const float* wq        = (const float*)d_in[5];
  const float* wk        = (const float*)d_in[6];
  const float* wv        = (const float*)d_in[7];
  const float* wu        = (const float*)d_in[8];
  const float* wo        = (const float*)d_in[9];
  const float* ts_w      = (const float*)d_in[10];
  const float* pos_w     = (const float*)d_in[11];

  // OUTPUTS ARE FLOAT32: out [4,1024,512] then attn [4,8,1024,1024]
  float* out  = (float*)d_out;
  float* attn = out + 2097152;

  // workspace (bf16 partials); ao2 overlays hb (dead by pv time)
  bf16* wb    = (bf16*)d_ws;           // 5 * 512*512
  bf16* hb    = wb + 5 * DIM * DIM;    // [4096,512]
  bf16* q     = hb + 2097152;          // [b,h,l,d]
  bf16* k     = q + 2097152;
  bf16* vT    = k + 2097152;           // [b,h,d,l] (written directly by gemm_qkvu)
  bf16* u     = vT + 2097152;          // [4096,512]
  bf16* gated = u + 2097152;           // [4096,512]
  bf16* ao0   = gated + 2097152;       // [4096,512] bf16
  bf16* ao1   = ao0 + 2097152;         // [4096,512] bf16
  bf16* ao2   = hb;                    // overlay: hb dead after qk_attn

  prep_k<<<2304, 256, 0, stream>>>(wq, wk, wv, wu, wo, wb, hidden, ln_w, hb);
  gemm_qkvu_k<<<dim3(256, 4), 256, 0, stream>>>(hb, wb, q, k, vT, u);
  qk_attn_k<<<dim3(36, 32), 256, 0, stream>>>(q, k, ts, ts_w, pos_w, attn);
  pv_k<<<dim3(17, 32), 256, 0, stream>>>(attn, vT, ao0, ao1, ao2);
  gated_k<<<4096, 64, 0, stream>>>(ao0, ao1, ao2, u, attn_ln_w, gated);
  gemm_out_k<<<256, 256, 0, stream>>>(gated, wb + 4 * DIM * DIM, hidden, out);
}